// Round 8
// baseline (63.183 us; speedup 1.0000x reference)
//
#include <hip/hip_runtime.h>
#include <math.h>

#define CIN  32
#define COUT 32
#define BB   4
#define HH   80
#define WW   80
#define HW   (HH * WW)
#define TH   16                 // output rows per block
#define XR   20                 // haloed rows
#define XC   88                 // haloed cols, padded: stride 88 dw == 24 mod 32 banks
#define TILE (XR * XC)          // 1760
#define NT   320                // 16 rows x 20 col-groups (4 cols each)

typedef float v4f __attribute__((ext_vector_type(4)));

__device__ __forceinline__ float max3f(float a, float b, float c) {
    float d;
    asm("v_max3_f32 %0, %1, %2, %3" : "=v"(d) : "v"(a), "v"(b), "v"(c));
    return d;
}

__device__ __forceinline__ void load_lds4(const float* g, float* l) {
    __builtin_amdgcn_global_load_lds(
        (const __attribute__((address_space(1))) void*)g,
        (__attribute__((address_space(3))) void*)l, 4, 0, 0);
}

// One block: 16x80 stripe, co-PAIR (x LDS reads amortized over 2 co), ci-chunk
// of CIN/NP. x staged via global_load_lds (lane-linear dest; OOB cells
// prefilled -inf once). Weights: coalesced global read scattered once into
// interleaved LDS layout [k][m][12]. Partials accumulated into d_out via
// fp32 atomicAdd (out zeroed by memset; part 0 contributes the bias).
// NO d_ws use: the harness's 256 MiB workspace poison-fill (~39 us) was
// pipelining with replays and flooring dur_us at ~38.2 us in rounds 3-7.
template<int NP>
__global__ __launch_bounds__(NT, 6) void semiconv_kernel(
    const float* __restrict__ x,     // [B, CIN, H, W]
    const float* __restrict__ w,     // [COUT, CIN, 5, 5]
    const float* __restrict__ bias,  // [COUT]
    float* __restrict__ out)         // [B, COUT, H, W], pre-zeroed
{
    constexpr int CP = CIN / NP;
    __shared__ __align__(16) float xs0[TILE];
    __shared__ __align__(16) float xs1[TILE];
    __shared__ __align__(16) float wl[CP * 60];   // [k][m][12]: (co0,co1) pairs n=0..4 + 2 pad

    const int tid = threadIdx.x;
    const int bh  = blockIdx.x;               // 0..4 row stripe
    const int cp  = blockIdx.y;               // 0..15 co-pair
    const int zz  = blockIdx.z;               // b * NP + part
    const int b    = zz / NP;
    const int part = zz % NP;
    const int ci0  = part * CP;
    const int h0   = bh * TH;
    const int co0  = cp * 2;

    // ---- coalesced weight staging: two contiguous 200-float runs ----
    for (int idx = tid; idx < CP * 50; idx += NT) {
        int run = idx / (CP * 25);            // which co of the pair
        int r   = idx % (CP * 25);            // flat within (ci-chunk, 25 taps)
        int k = r / 25, t = r % 25, m = t / 5, n = t % 5;
        float v = w[((size_t)(co0 + run) * CIN + ci0) * 25 + r];  // contiguous in r
        wl[k * 60 + m * 12 + n * 2 + run] = v;
    }

    const int ty = tid / 20, tx = tid % 20, wc = tx * 4;

    // ---- per-chunk offsets; -inf prefill of ci-invariant OOB/pad cells ----
    int goff[6];
    #pragma unroll
    for (int i = 0; i < 6; ++i) {
        int idx = tid + i * NT;
        int r = idx / XC, c = idx % XC;
        int gr = h0 + r - 2, gc = c - 2;
        bool in = (idx < TILE) && gr >= 0 && gr < HH && gc >= 0 && gc < WW;
        goff[i] = in ? (gr * WW + gc) : -1;
        if (idx < TILE && !in) { xs0[idx] = -INFINITY; xs1[idx] = -INFINITY; }
    }
    const bool has6 = (tid < TILE - 5 * NT);   // tid < 160

    const float* xbase = x + (size_t)(b * CIN + ci0) * HW;
    const int wave64 = tid & ~63;

    // ---- stage tile k=0 into xs0 ----
    #pragma unroll
    for (int i = 0; i < 5; ++i)
        if (goff[i] >= 0) load_lds4(xbase + goff[i], xs0 + i * NT + wave64);
    if (has6 && goff[5] >= 0) load_lds4(xbase + goff[5], xs0 + 5 * NT + wave64);

    const float* xnext = xbase + HW;
    float sA[4] = {0.f, 0.f, 0.f, 0.f}, sB[4] = {0.f, 0.f, 0.f, 0.f};
    const int xro = ty * XC + wc;

    __syncthreads();   // weights + -inf prefill + tile 0 complete

    auto step = [&](int k, const float* xrd, float* xwr) {
        if (k + 1 < CP) {                     // prefetch next tile under compute
            #pragma unroll
            for (int i = 0; i < 5; ++i)
                if (goff[i] >= 0) load_lds4(xnext + goff[i], xwr + i * NT + wave64);
            if (has6 && goff[5] >= 0) load_lds4(xnext + goff[5], xwr + 5 * NT + wave64);
            xnext += HW;
        }
        const float* wk = &wl[k * 60];
        float aA[4] = {-INFINITY, -INFINITY, -INFINITY, -INFINITY};
        float aB[4] = {-INFINITY, -INFINITY, -INFINITY, -INFINITY};
        #pragma unroll
        for (int m = 0; m < 5; ++m) {
            v4f A  = *(const v4f*)(xrd + xro + m * XC);
            v4f C  = *(const v4f*)(xrd + xro + m * XC + 4);
            v4f W0 = *(const v4f*)(wk + m * 12);
            v4f W1 = *(const v4f*)(wk + m * 12 + 4);
            v4f W2 = *(const v4f*)(wk + m * 12 + 8);
            float xr[8] = {A.x, A.y, A.z, A.w, C.x, C.y, C.z, C.w};
            float wa[5] = {W0.x, W0.z, W1.x, W1.z, W2.x};
            float wb[5] = {W0.y, W0.w, W1.y, W1.w, W2.y};
            #pragma unroll
            for (int j = 0; j < 4; ++j) {
                float p0 = xr[j] + wa[0], p1 = xr[j+1] + wa[1], p2 = xr[j+2] + wa[2];
                float p3 = xr[j+3] + wa[3], p4 = xr[j+4] + wa[4];
                aA[j] = max3f(aA[j], max3f(p0, p1, p2), fmaxf(p3, p4));
                p0 = xr[j] + wb[0]; p1 = xr[j+1] + wb[1]; p2 = xr[j+2] + wb[2];
                p3 = xr[j+3] + wb[3]; p4 = xr[j+4] + wb[4];
                aB[j] = max3f(aB[j], max3f(p0, p1, p2), fmaxf(p3, p4));
            }
        }
        #pragma unroll
        for (int j = 0; j < 4; ++j) { sA[j] += aA[j]; sB[j] += aB[j]; }
        __syncthreads();   // next tile landed + all reads of xrd done
    };

    #pragma unroll 1
    for (int k = 0; k < CP; k += 2) {
        step(k,     xs0, xs1);
        step(k + 1, xs1, xs0);
    }

    // ---- epilogue: accumulate into out (part 0 carries the bias) ----
    size_t oiA = (((size_t)b * COUT + co0) * HH + (h0 + ty)) * WW + wc;
    size_t oiB = oiA + (size_t)HW;            // co0+1
    float addA = 0.f, addB = 0.f;
    if (NP == 1 || part == 0) { addA = bias[co0]; addB = bias[co0 + 1]; }
    if (NP == 1) {
        v4f rA = {sA[0] + addA, sA[1] + addA, sA[2] + addA, sA[3] + addA};
        v4f rB = {sB[0] + addB, sB[1] + addB, sB[2] + addB, sB[3] + addB};
        *(v4f*)(out + oiA) = rA;
        *(v4f*)(out + oiB) = rB;
    } else {
        #pragma unroll
        for (int j = 0; j < 4; ++j) {
            atomicAdd(out + oiA + j, sA[j] + addA);
            atomicAdd(out + oiB + j, sB[j] + addB);
        }
    }
}

extern "C" void kernel_launch(void* const* d_in, const int* in_sizes, int n_in,
                              void* d_out, int out_size, void* d_ws, size_t ws_size,
                              hipStream_t stream) {
    const float* x    = (const float*)d_in[0];
    const float* w    = (const float*)d_in[1];
    const float* bias = (const float*)d_in[2];
    float* out        = (float*)d_out;

    // zero d_out, then all ci-chunks atomically accumulate (replay-idempotent)
    hipMemsetAsync(d_out, 0, (size_t)out_size * sizeof(float), stream);
    dim3 grid(HH / TH, COUT / 2, BB * 4);          // 5 x 16 x 16 = 1280 blocks
    semiconv_kernel<4><<<grid, NT, 0, stream>>>(x, w, bias, out);
}

// Round 9
// 44.506 us; speedup vs baseline: 1.4197x; 1.4197x over previous
//
#include <hip/hip_runtime.h>
#include <math.h>

#define CIN  32
#define COUT 32
#define BB   4
#define HH   80
#define WW   80
#define HW   (HH * WW)
#define NOUT (BB * COUT * HW)   // 819200
#define TH   16                 // output rows per block
#define XR   20                 // haloed rows
#define XC   88                 // haloed cols, padded (stride 88 dw == 24 mod 32 banks)
#define TILE (XR * XC)          // 1760
#define NT   320                // 16 rows x 20 col-groups (4 cols each)

typedef float v4f __attribute__((ext_vector_type(4)));

__device__ __forceinline__ float max3f(float a, float b, float c) {
    float d;
    asm("v_max3_f32 %0, %1, %2, %3" : "=v"(d) : "v"(a), "v"(b), "v"(c));
    return d;
}

__device__ __forceinline__ void load_lds4(const float* g, float* l) {
    __builtin_amdgcn_global_load_lds(
        (const __attribute__((address_space(1))) void*)g,
        (__attribute__((address_space(3))) void*)l, 4, 0, 0);
}

// One block: 16x80 stripe, co-QUAD (x LDS reads amortized over 4 co), ci-chunk
// of CIN/NP. x staged via global_load_lds (lane-linear dest; OOB cells
// prefilled -inf once). Weights: coalesced global read scattered once into
// LDS layout [k][m][20] = (n*4+co'), read as 5 broadcast b128 per m.
// Partials to d_ws (NP>1), summed by reduceN. No atomics (R8: +25us L2 RMW).
template<int NP>
__global__ __launch_bounds__(NT, 6) void semiconv_kernel(
    const float* __restrict__ x,     // [B, CIN, H, W]
    const float* __restrict__ w,     // [COUT, CIN, 5, 5]
    const float* __restrict__ bias,  // [COUT]
    float* __restrict__ dst)         // out (NP==1) or partials [NP][NOUT]
{
    constexpr int CP = CIN / NP;
    __shared__ __align__(16) float xs0[TILE];
    __shared__ __align__(16) float xs1[TILE];
    __shared__ __align__(16) float wl[CP * 100];  // [k][m][20]: n*4+co'

    const int tid = threadIdx.x;
    const int bh  = blockIdx.x;               // 0..4 row stripe
    const int cq  = blockIdx.y;               // 0..7 co-quad
    const int zz  = blockIdx.z;               // b * NP + part
    const int b    = zz / NP;
    const int part = zz % NP;
    const int ci0  = part * CP;
    const int h0   = bh * TH;
    const int co0  = cq * 4;

    // ---- coalesced weight staging: four contiguous CP*25-float runs ----
    for (int idx = tid; idx < CP * 100; idx += NT) {
        int cop = idx / (CP * 25);            // which co of the quad
        int r   = idx % (CP * 25);            // contiguous within (ci-chunk, taps)
        int k = r / 25, t = r % 25, m = t / 5, n = t % 5;
        wl[k * 100 + m * 20 + n * 4 + cop] =
            w[((size_t)(co0 + cop) * CIN + ci0) * 25 + r];
    }

    const int ty = tid / 20, tx = tid % 20, wc = tx * 4;

    // ---- per-chunk offsets; -inf prefill of ci-invariant OOB/pad cells ----
    int goff[6];
    #pragma unroll
    for (int i = 0; i < 6; ++i) {
        int idx = tid + i * NT;
        int r = idx / XC, c = idx % XC;
        int gr = h0 + r - 2, gc = c - 2;
        bool in = (idx < TILE) && gr >= 0 && gr < HH && gc >= 0 && gc < WW;
        goff[i] = in ? (gr * WW + gc) : -1;
        if (idx < TILE && !in) { xs0[idx] = -INFINITY; xs1[idx] = -INFINITY; }
    }
    const bool has6 = (tid < TILE - 5 * NT);   // tid < 160

    const float* xbase = x + (size_t)(b * CIN + ci0) * HW;
    const int wave64 = tid & ~63;

    // ---- stage tile k=0 into xs0 ----
    #pragma unroll
    for (int i = 0; i < 5; ++i)
        if (goff[i] >= 0) load_lds4(xbase + goff[i], xs0 + i * NT + wave64);
    if (has6 && goff[5] >= 0) load_lds4(xbase + goff[5], xs0 + 5 * NT + wave64);

    const float* xnext = xbase + HW;
    float s[4][4];
    #pragma unroll
    for (int c = 0; c < 4; ++c)
        #pragma unroll
        for (int j = 0; j < 4; ++j) s[c][j] = 0.f;
    const int xro = ty * XC + wc;

    __syncthreads();   // weights + -inf prefill + tile 0 complete

    auto step = [&](int k, const float* xrd, float* xwr) {
        if (k + 1 < CP) {                     // prefetch next tile under compute
            #pragma unroll
            for (int i = 0; i < 5; ++i)
                if (goff[i] >= 0) load_lds4(xnext + goff[i], xwr + i * NT + wave64);
            if (has6 && goff[5] >= 0) load_lds4(xnext + goff[5], xwr + 5 * NT + wave64);
            xnext += HW;
        }
        const float* wk = &wl[k * 100];
        float acc[4][4];
        #pragma unroll
        for (int c = 0; c < 4; ++c)
            #pragma unroll
            for (int j = 0; j < 4; ++j) acc[c][j] = -INFINITY;

        #pragma unroll
        for (int m = 0; m < 5; ++m) {
            v4f A = *(const v4f*)(xrd + xro + m * XC);
            v4f C = *(const v4f*)(xrd + xro + m * XC + 4);
            float xr[8] = {A.x, A.y, A.z, A.w, C.x, C.y, C.z, C.w};
            v4f W0 = *(const v4f*)(wk + m * 20);       // n=0, co'0..3
            v4f W1 = *(const v4f*)(wk + m * 20 + 4);   // n=1
            v4f W2 = *(const v4f*)(wk + m * 20 + 8);   // n=2
            v4f W3 = *(const v4f*)(wk + m * 20 + 12);  // n=3
            v4f W4 = *(const v4f*)(wk + m * 20 + 16);  // n=4
            float wn0[4] = {W0.x, W0.y, W0.z, W0.w};
            float wn1[4] = {W1.x, W1.y, W1.z, W1.w};
            float wn2[4] = {W2.x, W2.y, W2.z, W2.w};
            float wn3[4] = {W3.x, W3.y, W3.z, W3.w};
            float wn4[4] = {W4.x, W4.y, W4.z, W4.w};
            #pragma unroll
            for (int c = 0; c < 4; ++c) {
                #pragma unroll
                for (int j = 0; j < 4; ++j) {
                    float p0 = xr[j]     + wn0[c];
                    float p1 = xr[j + 1] + wn1[c];
                    float p2 = xr[j + 2] + wn2[c];
                    float p3 = xr[j + 3] + wn3[c];
                    float p4 = xr[j + 4] + wn4[c];
                    acc[c][j] = max3f(acc[c][j], max3f(p0, p1, p2), fmaxf(p3, p4));
                }
            }
        }
        #pragma unroll
        for (int c = 0; c < 4; ++c)
            #pragma unroll
            for (int j = 0; j < 4; ++j) s[c][j] += acc[c][j];
        __syncthreads();   // next tile landed + all reads of xrd done
    };

    #pragma unroll 1
    for (int k = 0; k < CP; k += 2) {         // CP even for NP in {1,4,8}
        step(k,     xs0, xs1);
        step(k + 1, xs1, xs0);
    }

    // ---- epilogue: 4 co rows, b128 stores ----
    size_t oi = (((size_t)b * COUT + co0) * HH + (h0 + ty)) * WW + wc;
    float* o = (NP == 1) ? dst : dst + (size_t)part * NOUT;
    #pragma unroll
    for (int c = 0; c < 4; ++c) {
        float add = (NP == 1) ? bias[co0 + c] : 0.f;
        v4f r = {s[c][0] + add, s[c][1] + add, s[c][2] + add, s[c][3] + add};
        *(v4f*)(o + oi + (size_t)c * HW) = r;
    }
}

template<int NP>
__global__ __launch_bounds__(256) void reduceN_kernel(
    const float* __restrict__ ws, const float* __restrict__ bias,
    float* __restrict__ out)
{
    int i4 = blockIdx.x * 256 + threadIdx.x;        // 0..204799
    const float4* p = reinterpret_cast<const float4*>(ws);
    float4 r = p[i4];
    #pragma unroll
    for (int q = 1; q < NP; ++q) {
        float4 t = p[i4 + (size_t)q * (NOUT / 4)];
        r.x += t.x; r.y += t.y; r.z += t.z; r.w += t.w;
    }
    int co = (i4 / (HW / 4)) & (COUT - 1);
    float bc = bias[co];
    r.x += bc; r.y += bc; r.z += bc; r.w += bc;
    reinterpret_cast<float4*>(out)[i4] = r;
}

extern "C" void kernel_launch(void* const* d_in, const int* in_sizes, int n_in,
                              void* d_out, int out_size, void* d_ws, size_t ws_size,
                              hipStream_t stream) {
    const float* x    = (const float*)d_in[0];
    const float* w    = (const float*)d_in[1];
    const float* bias = (const float*)d_in[2];
    float* out        = (float*)d_out;

    const size_t need8 = 8ull * NOUT * sizeof(float);  // 26.2 MB
    const size_t need4 = 4ull * NOUT * sizeof(float);  // 13.1 MB

    if (ws_size >= need8) {
        dim3 grid(HH / TH, COUT / 4, BB * 8);          // 5 x 8 x 32 = 1280 blocks
        semiconv_kernel<8><<<grid, NT, 0, stream>>>(x, w, bias, (float*)d_ws);
        reduceN_kernel<8><<<NOUT / 4 / 256, 256, 0, stream>>>((const float*)d_ws, bias, out);
    } else if (ws_size >= need4) {
        dim3 grid(HH / TH, COUT / 4, BB * 4);          // 640 blocks
        semiconv_kernel<4><<<grid, NT, 0, stream>>>(x, w, bias, (float*)d_ws);
        reduceN_kernel<4><<<NOUT / 4 / 256, 256, 0, stream>>>((const float*)d_ws, bias, out);
    } else {
        dim3 grid(HH / TH, COUT / 4, BB);              // 160 blocks fallback
        semiconv_kernel<1><<<grid, NT, 0, stream>>>(x, w, bias, out);
    }
}

// Round 10
// 42.793 us; speedup vs baseline: 1.4765x; 1.0400x over previous
//
#include <hip/hip_runtime.h>
#include <math.h>

#define CIN  32
#define COUT 32
#define BB   4
#define HH   80
#define WW   80
#define HW   (HH * WW)
#define NOUT (BB * COUT * HW)   // 819200
#define TH   16                 // output rows per block
#define XR   20                 // haloed rows
#define XC   88                 // haloed cols, padded (stride 88 dw == 24 mod 32 banks)
#define TILE (XR * XC)          // 1760
#define NT   320                // 16 rows x 20 col-groups (4 cols each)

typedef float v4f __attribute__((ext_vector_type(4)));

__device__ __forceinline__ float max3f(float a, float b, float c) {
    float d;
    asm("v_max3_f32 %0, %1, %2, %3" : "=v"(d) : "v"(a), "v"(b), "v"(c));
    return d;
}

__device__ __forceinline__ void load_lds4(const float* g, float* l) {
    __builtin_amdgcn_global_load_lds(
        (const __attribute__((address_space(1))) void*)g,
        (__attribute__((address_space(3))) void*)l, 4, 0, 0);
}

// One block: 16x80 stripe, co-QUAD, ci-chunk of CP=CIN/NP channels.
// ALL CP x-tiles resident in LDS at once -> single barrier, no double-buffer,
// no mid-loop vmcnt drains. k fully unrolled -> every LDS access is one base
// register + immediate offset. Weights [k][m][20] (n*4+co'), 5 broadcast b128
// per m, components register-addressed. Partials to d_ws, summed by reduceN.
template<int NP>
__global__ __launch_bounds__(NT, 6) void semiconv_kernel(
    const float* __restrict__ x,     // [B, CIN, H, W]
    const float* __restrict__ w,     // [COUT, CIN, 5, 5]
    float* __restrict__ dst)         // partials [NP][NOUT]
{
    constexpr int CP = CIN / NP;
    __shared__ __align__(16) float xs[CP][TILE];
    __shared__ __align__(16) float wl[CP * 100];  // [k][m][20]: n*4+co'

    const int tid = threadIdx.x;
    const int bh  = blockIdx.x;               // 0..4 row stripe
    const int cq  = blockIdx.y;               // 0..7 co-quad
    const int zz  = blockIdx.z;               // b * NP + part
    const int b    = zz / NP;
    const int part = zz % NP;
    const int ci0  = part * CP;
    const int h0   = bh * TH;
    const int co0  = cq * 4;

    const int ty = tid / 20, tx = tid % 20, wc = tx * 4;
    const int xro = ty * XC + wc;

    // ---- per-chunk offsets ----
    int goff[6];
    #pragma unroll
    for (int i = 0; i < 6; ++i) {
        int idx = tid + i * NT;
        int r = idx / XC, c = idx % XC;
        int gr = h0 + r - 2, gc = c - 2;
        bool in = (idx < TILE) && gr >= 0 && gr < HH && gc >= 0 && gc < WW;
        goff[i] = in ? (gr * WW + gc) : -1;
    }
    const bool has6 = (tid < TILE - 5 * NT);   // tid < 160

    // ---- issue ALL tile DMAs up front ----
    const float* xb0 = x + (size_t)(b * CIN + ci0) * HW;
    const int wave64 = tid & ~63;
    #pragma unroll
    for (int t = 0; t < CP; ++t) {
        const float* xp = xb0 + (size_t)t * HW;
        #pragma unroll
        for (int i = 0; i < 5; ++i)
            if (goff[i] >= 0) load_lds4(xp + goff[i], &xs[t][i * NT + wave64]);
        if (has6 && goff[5] >= 0) load_lds4(xp + goff[5], &xs[t][5 * NT + wave64]);
    }

    // ---- weight staging (coalesced global reads), overlaps DMA flight ----
    for (int idx = tid; idx < CP * 100; idx += NT) {
        int cop = idx / (CP * 25);
        int r   = idx % (CP * 25);
        int k = r / 25, t = r % 25, m = t / 5, n = t % 5;
        wl[k * 100 + m * 20 + n * 4 + cop] =
            w[((size_t)(co0 + cop) * CIN + ci0) * 25 + r];
    }

    // ---- -inf prefill of OOB/pad cells (disjoint from DMA slots) ----
    #pragma unroll
    for (int i = 0; i < 6; ++i) {
        int idx = tid + i * NT;
        if (idx < TILE && goff[i] < 0) {
            #pragma unroll
            for (int t = 0; t < CP; ++t) xs[t][idx] = -INFINITY;
        }
    }

    float s[4][4];
    #pragma unroll
    for (int c = 0; c < 4; ++c)
        #pragma unroll
        for (int j = 0; j < 4; ++j) s[c][j] = 0.f;

    __syncthreads();   // the ONLY barrier: weights + prefill + all DMAs done

    #pragma unroll
    for (int k = 0; k < CP; ++k) {
        const float* xb = &xs[k][xro];
        const float* wk = &wl[k * 100];
        float acc[4][4];
        #pragma unroll
        for (int m = 0; m < 5; ++m) {
            v4f A  = *(const v4f*)(xb + m * XC);
            v4f C  = *(const v4f*)(xb + m * XC + 4);
            v4f W0 = *(const v4f*)(wk + m * 20);
            v4f W1 = *(const v4f*)(wk + m * 20 + 4);
            v4f W2 = *(const v4f*)(wk + m * 20 + 8);
            v4f W3 = *(const v4f*)(wk + m * 20 + 12);
            v4f W4 = *(const v4f*)(wk + m * 20 + 16);
            float xr[8] = {A.x, A.y, A.z, A.w, C.x, C.y, C.z, C.w};
            #pragma unroll
            for (int c = 0; c < 4; ++c) {
                float q0 = W0[c], q1 = W1[c], q2 = W2[c], q3 = W3[c], q4 = W4[c];
                #pragma unroll
                for (int j = 0; j < 4; ++j) {
                    float t = max3f(xr[j] + q0, xr[j + 1] + q1, xr[j + 2] + q2);
                    float u = fmaxf(xr[j + 3] + q3, xr[j + 4] + q4);
                    acc[c][j] = (m == 0) ? fmaxf(t, u) : max3f(acc[c][j], t, u);
                }
            }
        }
        #pragma unroll
        for (int c = 0; c < 4; ++c)
            #pragma unroll
            for (int j = 0; j < 4; ++j) s[c][j] += acc[c][j];
    }

    // ---- epilogue: 4 co rows of partials, b128 stores ----
    size_t oi = (((size_t)b * COUT + co0) * HH + (h0 + ty)) * WW + wc;
    float* o = dst + (size_t)part * NOUT;
    #pragma unroll
    for (int c = 0; c < 4; ++c) {
        v4f r = {s[c][0], s[c][1], s[c][2], s[c][3]};
        *(v4f*)(o + oi + (size_t)c * HW) = r;
    }
}

template<int NP>
__global__ __launch_bounds__(256) void reduceN_kernel(
    const float* __restrict__ ws, const float* __restrict__ bias,
    float* __restrict__ out)
{
    int i4 = blockIdx.x * 256 + threadIdx.x;        // 0..204799
    const float4* p = reinterpret_cast<const float4*>(ws);
    float4 r = p[i4];
    #pragma unroll
    for (int q = 1; q < NP; ++q) {
        float4 t = p[i4 + (size_t)q * (NOUT / 4)];
        r.x += t.x; r.y += t.y; r.z += t.z; r.w += t.w;
    }
    int co = (i4 / (HW / 4)) & (COUT - 1);
    float bc = bias[co];
    r.x += bc; r.y += bc; r.z += bc; r.w += bc;
    reinterpret_cast<float4*>(out)[i4] = r;
}

// Last-resort correct path (never used when ws is the usual 256 MiB).
__global__ __launch_bounds__(256) void naive_kernel(
    const float* __restrict__ x, const float* __restrict__ w,
    const float* __restrict__ bias, float* __restrict__ out)
{
    int o = blockIdx.x * 256 + threadIdx.x;
    if (o >= NOUT) return;
    int wcol = o % WW, h = (o / WW) % HH, co = (o / HW) % COUT, b = o / (COUT * HW);
    float sum = 0.f;
    for (int ci = 0; ci < CIN; ++ci) {
        float mx = -INFINITY;
        for (int m = 0; m < 5; ++m) {
            int gr = h + m - 2;
            if (gr < 0 || gr >= HH) continue;
            for (int n = 0; n < 5; ++n) {
                int gc = wcol + n - 2;
                if (gc < 0 || gc >= WW) continue;
                float v = x[((size_t)(b * CIN + ci)) * HW + gr * WW + gc]
                        + w[((size_t)(co * CIN + ci)) * 25 + m * 5 + n];
                mx = fmaxf(mx, v);
            }
        }
        sum += mx;
    }
    out[o] = sum + bias[co];
}

extern "C" void kernel_launch(void* const* d_in, const int* in_sizes, int n_in,
                              void* d_out, int out_size, void* d_ws, size_t ws_size,
                              hipStream_t stream) {
    const float* x    = (const float*)d_in[0];
    const float* w    = (const float*)d_in[1];
    const float* bias = (const float*)d_in[2];
    float* out        = (float*)d_out;

    const size_t need8 = 8ull * NOUT * sizeof(float);  // 26.2 MB
    const size_t need4 = 4ull * NOUT * sizeof(float);  // 13.1 MB

    if (ws_size >= need8) {
        dim3 grid(HH / TH, COUT / 4, BB * 8);          // 5 x 8 x 32 = 1280 blocks
        semiconv_kernel<8><<<grid, NT, 0, stream>>>(x, w, (float*)d_ws);
        reduceN_kernel<8><<<NOUT / 4 / 256, 256, 0, stream>>>((const float*)d_ws, bias, out);
    } else if (ws_size >= need4) {
        dim3 grid(HH / TH, COUT / 4, BB * 4);          // 640 blocks (CP=8: 58 KB LDS)
        semiconv_kernel<4><<<grid, NT, 0, stream>>>(x, w, (float*)d_ws);
        reduceN_kernel<4><<<NOUT / 4 / 256, 256, 0, stream>>>((const float*)d_ws, bias, out);
    } else {
        naive_kernel<<<(NOUT + 255) / 256, 256, 0, stream>>>(x, w, bias, out);
    }
}